// Round 5
// baseline (2808.226 us; speedup 1.0000x reference)
//
#include <hip/hip_runtime.h>
#include <math.h>
#include <stdint.h>

typedef float f32x4 __attribute__((ext_vector_type(4)));
typedef short short8 __attribute__((ext_vector_type(8)));

#define GLOBAL_AS __attribute__((address_space(1)))
#define LDS_AS __attribute__((address_space(3)))

static constexpr int HWo   = 3136;   // 56*56
static constexpr int NB    = 8;
static constexpr int NP    = 3200;   // padded pixel/centroid count (25*128)
static constexpr int KDIM  = 1794;   // 1792 + 2 coord channels
static constexpr int KP1   = 1856;   // gemm1 K padded to 29*64
static constexpr int ODIM  = 1792;   // gemm2 K = 28*64
static constexpr int NCENT = 3136;

__device__ __forceinline__ uint16_t f2bf(float f) {
  union { float f; uint32_t u; } v; v.f = f;
  uint32_t u = v.u;
  return (uint16_t)((u + 0x7FFFu + ((u >> 16) & 1u)) >> 16);   // RNE
}
__device__ __forceinline__ float bf2f(uint16_t h) {
  union { uint32_t u; float f; } v; v.u = ((uint32_t)h) << 16;
  return v.f;
}

// ---------------- one-time converts ----------------
__global__ __launch_bounds__(256) void convW_kernel(const float* __restrict__ W, uint16_t* __restrict__ Wh) {
  int idx = blockIdx.x * 256 + threadIdx.x;          // 1792*1856 exact
  int o = idx / KP1, k = idx % KP1;
  float v = (k < KDIM) ? W[(size_t)o * KDIM + k] : 0.f;
  Wh[idx] = f2bf(v);
}

__global__ __launch_bounds__(256) void convC_kernel(const float* __restrict__ C, uint16_t* __restrict__ Ct) {
  int idx = blockIdx.x * 256 + threadIdx.x;          // 3136*1792 exact
  int j = idx / ODIM, o = idx % ODIM;
  Ct[(size_t)j * ODIM + o] = f2bf(C[(size_t)o * NCENT + j]);
}

// cent[j] = |C_col_j|^2 for j<3136, 1e30 sentinel for padded rows
__global__ __launch_bounds__(256) void cent_kernel(const uint16_t* __restrict__ Ct, float* __restrict__ cent) {
  int t = threadIdx.x, lane = t & 63, wv = t >> 6;
  int row = blockIdx.x * 4 + wv;                     // 800 blocks -> 3200 rows
  if (row >= NCENT) { if (lane == 0) cent[row] = 1e30f; return; }
  const uint32_t* p = (const uint32_t*)(Ct + (size_t)row * ODIM);
  float s = 0.f;
  #pragma unroll
  for (int it = 0; it < 14; ++it) {
    uint32_t u = p[it * 64 + lane];
    float a = bf2f((uint16_t)(u & 0xFFFF)), b = bf2f((uint16_t)(u >> 16));
    s += a * a + b * b;
  }
  #pragma unroll
  for (int m = 1; m < 64; m <<= 1) s += __shfl_xor(s, m, 64);
  if (lane == 0) cent[row] = s;
}

// ---------------- pooling (all 3 levels, native res, fp32) ----------------
static constexpr int P1SZ = 256 * 3136;
static constexpr int P2SZ = 512 * 784;
static constexpr int P3SZ = 1024 * 196;

__device__ __forceinline__ float pool9f(const float* __restrict__ p, int S, int y, int x) {
  float s = 0.f;
  for (int dy = -1; dy <= 1; ++dy) {
    int yy = y + dy; if (yy < 0 || yy >= S) continue;
    for (int dx = -1; dx <= 1; ++dx) {
      int xx = x + dx; if (xx < 0 || xx >= S) continue;
      s += p[yy * S + xx];
    }
  }
  return s * (1.f / 9.f);
}

__global__ __launch_bounds__(256) void pool_kernel(const float* __restrict__ p1, const float* __restrict__ p2,
                                                   const float* __restrict__ p3, float* __restrict__ pooled, int b) {
  int idx = blockIdx.x * 256 + threadIdx.x;          // 1404928 exact
  const float* src; int S, loc;
  if (idx < P1SZ)              { src = p1 + (size_t)b * P1SZ; S = 56; loc = idx; }
  else if (idx < P1SZ + P2SZ)  { src = p2 + (size_t)b * P2SZ; S = 28; loc = idx - P1SZ; }
  else                         { src = p3 + (size_t)b * P3SZ; S = 14; loc = idx - P1SZ - P2SZ; }
  int c = loc / (S * S), hw = loc % (S * S);
  pooled[idx] = pool9f(src + (size_t)c * S * S, S, hw / S, hw % S);
}

// ---------------- assemble xcb bf16 [3200][1856] pixel-major; also zero feat ----------------
__global__ __launch_bounds__(256) void assemble_kernel(const float* __restrict__ pooled, uint16_t* __restrict__ xcb,
                                                       float* __restrict__ feat) {
  int idx = blockIdx.x * 256 + threadIdx.x;          // 3136*1856 exact
  if (idx < NP) feat[idx] = 0.f;                     // zero feat for gemm1 atomics
  int i = idx / KP1, ch = idx % KP1;
  int x = i % 56, y = i / 56;
  float v;
  if (ch < 256) {
    v = pooled[ch * 3136 + i];
  } else if (ch < 1792) {
    const float* base; int S; float scale, shift;
    if (ch < 768) { base = pooled + P1SZ + (ch - 256) * 784;          S = 28; scale = 0.5f;  shift = -0.25f;  }
    else          { base = pooled + P1SZ + P2SZ + (ch - 768) * 196;   S = 14; scale = 0.25f; shift = -0.375f; }
    float sx = x * scale + shift, sy = y * scale + shift;
    float fx0 = floorf(sx), fy0 = floorf(sy);
    float fx = sx - fx0, fy = sy - fy0;
    int x0 = (int)fx0, y0 = (int)fy0, x1 = x0 + 1, y1 = y0 + 1;
    x0 = x0 < 0 ? 0 : x0; x1 = x1 > S - 1 ? S - 1 : x1;
    y0 = y0 < 0 ? 0 : y0; y1 = y1 > S - 1 ? S - 1 : y1;
    float v00 = base[y0 * S + x0], v01 = base[y0 * S + x1];
    float v10 = base[y1 * S + x0], v11 = base[y1 * S + x1];
    v = (1.f - fy) * ((1.f - fx) * v00 + fx * v01) + fy * ((1.f - fx) * v10 + fx * v11);
  } else if (ch == 1792) v = -1.f + 2.f * x / 55.f;
  else if (ch == 1793)   v = -1.f + 2.f * y / 55.f;
  else                   v = 0.f;                    // K padding: MUST be zero
  xcb[idx] = f2bf(v);
}

// ---------------- shared GEMM building blocks ----------------
// Stage a 128x64(bf16) tile via global_load_lds(16B) with XOR-8 chunk swizzle:
// LDS slot (r, c) holds global chunk c^(r&7) of row r. Linear LDS = lane-order (no pad).
__device__ __forceinline__ void stage_tile(uint16_t* lds, const uint16_t* __restrict__ g, int ldk, int t) {
  int wv = t >> 6;
  #pragma unroll
  for (int it = 0; it < 4; ++it) {
    int idx = it * 256 + t;                          // [0,1024): r=idx>>3, c=idx&7
    int r = idx >> 3, c = idx & 7;
    int cg = c ^ (r & 7);
    const uint16_t* src = g + (size_t)r * ldk + cg * 8;
    uint16_t* dst = lds + (size_t)(it * 256 + wv * 64) * 8;   // wave-uniform base; HW adds lane*16
    __builtin_amdgcn_global_load_lds((const GLOBAL_AS void*)src, (LDS_AS void*)dst, 16, 0, 0);
  }
}

// Read 8-short fragment of logical chunk (kk*4+quad) of row r (undo swizzle)
__device__ __forceinline__ short8 frag_ld(const uint16_t* lds, int r, int kk, int quad) {
  int sc = (kk * 4 + quad) ^ (r & 7);
  return *(const short8*)(lds + r * 64 + sc * 8);
}

__device__ __forceinline__ void ins3(float v, float& a, float& b, float& c) {
  if (v < c) {
    if (v < b) { c = b; if (v < a) { b = a; a = v; } else { b = v; } }
    else { c = v; }
  }
}

// ---------------- GEMM1: phi_t[i][o] = W[o][:]·xc[i][:] + bias[o]; feat[i] += |phi_i|^2 ----------------
__global__ __launch_bounds__(256) void gemm1_mfma(const uint16_t* __restrict__ Wh, const float* __restrict__ bias,
                                                  const uint16_t* __restrict__ xcb, uint16_t* __restrict__ phi_t,
                                                  float* __restrict__ feat) {
  __shared__ uint16_t As[128 * 64];
  __shared__ uint16_t Bs[128 * 64];
  int t = threadIdx.x;
  int row0 = blockIdx.y * 128;     // o
  int col0 = blockIdx.x * 128;     // pixel
  int lane = t & 63, wv = t >> 6, wm = wv & 1, wn = wv >> 1;
  int l15 = lane & 15, quad = lane >> 4;
  f32x4 acc[4][4] = {};
  for (int k0 = 0; k0 < KP1; k0 += 64) {
    stage_tile(As, Wh + (size_t)row0 * KP1 + k0, KP1, t);
    stage_tile(Bs, xcb + (size_t)col0 * KP1 + k0, KP1, t);
    __syncthreads();
    #pragma unroll
    for (int kk = 0; kk < 2; ++kk) {
      short8 a[4], b[4];
      #pragma unroll
      for (int i = 0; i < 4; ++i) a[i] = frag_ld(As, wm * 64 + i * 16 + l15, kk, quad);
      #pragma unroll
      for (int j = 0; j < 4; ++j) b[j] = frag_ld(Bs, wn * 64 + j * 16 + l15, kk, quad);
      #pragma unroll
      for (int i = 0; i < 4; ++i)
        #pragma unroll
        for (int j = 0; j < 4; ++j)
          acc[i][j] = __builtin_amdgcn_mfma_f32_16x16x32_bf16(a[i], b[j], acc[i][j], 0, 0, 0);
    }
    __syncthreads();
  }
  // D: col(l15)=pixel, row(quad*4+reg)=o (verified round 4)
  float sq[4] = {0.f, 0.f, 0.f, 0.f};
  #pragma unroll
  for (int i = 0; i < 4; ++i) {
    int ob = row0 + wm * 64 + i * 16 + quad * 4;
    float4 bv = *(const float4*)&bias[ob];
    #pragma unroll
    for (int j = 0; j < 4; ++j) {
      int pix = col0 + wn * 64 + j * 16 + l15;
      float v0 = acc[i][j][0] + bv.x, v1 = acc[i][j][1] + bv.y;
      float v2 = acc[i][j][2] + bv.z, v3 = acc[i][j][3] + bv.w;
      ushort4 u; u.x = f2bf(v0); u.y = f2bf(v1); u.z = f2bf(v2); u.w = f2bf(v3);
      *(ushort4*)&phi_t[(size_t)pix * ODIM + ob] = u;
      sq[j] += v0 * v0 + v1 * v1 + v2 * v2 + v3 * v3;
    }
  }
  #pragma unroll
  for (int j = 0; j < 4; ++j) {
    sq[j] += __shfl_xor(sq[j], 16, 64);
    sq[j] += __shfl_xor(sq[j], 32, 64);
  }
  if (quad == 0) {
    #pragma unroll
    for (int j = 0; j < 4; ++j)
      atomicAdd(&feat[col0 + wn * 64 + j * 16 + l15], sq[j]);
  }
}

// ---------------- GEMM2 + fused per-block top-3: part[p][cb][3] = top3 of cent[q]-2*dot ----------------
__global__ __launch_bounds__(256) void gemm2_mfma(const uint16_t* __restrict__ phi_t, const uint16_t* __restrict__ Ct,
                                                  const float* __restrict__ cent, float* __restrict__ part) {
  __shared__ uint16_t As[128 * 64];
  __shared__ uint16_t Bs[128 * 64];
  int t = threadIdx.x;
  int row0 = blockIdx.y * 128;     // pixel
  int col0 = blockIdx.x * 128;     // centroid
  int lane = t & 63, wv = t >> 6, wm = wv & 1, wn = wv >> 1;
  int l15 = lane & 15, quad = lane >> 4;
  f32x4 acc[4][4] = {};
  for (int k0 = 0; k0 < ODIM; k0 += 64) {
    stage_tile(As, phi_t + (size_t)row0 * ODIM + k0, ODIM, t);
    stage_tile(Bs, Ct + (size_t)col0 * ODIM + k0, ODIM, t);
    __syncthreads();
    #pragma unroll
    for (int kk = 0; kk < 2; ++kk) {
      short8 a[4], b[4];
      #pragma unroll
      for (int i = 0; i < 4; ++i) a[i] = frag_ld(As, wm * 64 + i * 16 + l15, kk, quad);
      #pragma unroll
      for (int j = 0; j < 4; ++j) b[j] = frag_ld(Bs, wn * 64 + j * 16 + l15, kk, quad);
      #pragma unroll
      for (int i = 0; i < 4; ++i)
        #pragma unroll
        for (int j = 0; j < 4; ++j)
          acc[i][j] = __builtin_amdgcn_mfma_f32_16x16x32_bf16(a[i], b[j], acc[i][j], 0, 0, 0);
    }
    __syncthreads();
  }
  // D: col(l15)=centroid q, row(quad*4+reg)=pixel p. Thread: 16 pixels x 4 centroids.
  float T0[16], T1[16], T2[16];
  #pragma unroll
  for (int r = 0; r < 16; ++r) { T0[r] = 1e30f; T1[r] = 1e30f; T2[r] = 1e30f; }
  #pragma unroll
  for (int j = 0; j < 4; ++j) {
    float cv = cent[col0 + wn * 64 + j * 16 + l15];
    #pragma unroll
    for (int i = 0; i < 4; ++i)
      #pragma unroll
      for (int r = 0; r < 4; ++r) {
        float key = cv - 2.f * acc[i][j][r];       // rank-equal to dist^2 (feat added later)
        ins3(key, T0[i * 4 + r], T1[i * 4 + r], T2[i * 4 + r]);
      }
  }
  // merge across the 16 l15-lanes (xor bits 0..3 keep quad fixed)
  #pragma unroll
  for (int m = 1; m <= 8; m <<= 1) {
    #pragma unroll
    for (int r = 0; r < 16; ++r) {
      float u0 = __shfl_xor(T0[r], m, 64);
      float u1 = __shfl_xor(T1[r], m, 64);
      float u2 = __shfl_xor(T2[r], m, 64);
      ins3(u0, T0[r], T1[r], T2[r]);
      ins3(u1, T0[r], T1[r], T2[r]);
      ins3(u2, T0[r], T1[r], T2[r]);
    }
  }
  if (l15 == 0) {
    int cb = blockIdx.x * 2 + wn;                  // [0,50)
    #pragma unroll
    for (int i = 0; i < 4; ++i)
      #pragma unroll
      for (int r = 0; r < 4; ++r) {
        int p = row0 + wm * 64 + i * 16 + quad * 4 + r;
        float* pp = part + ((size_t)p * 50 + cb) * 3;
        pp[0] = T0[i * 4 + r]; pp[1] = T1[i * 4 + r]; pp[2] = T2[i * 4 + r];
      }
  }
}

// ---------------- merge 50 partial top-3 + softmin score, one wave per row ----------------
__global__ __launch_bounds__(256) void merge_score(const float* __restrict__ part, const float* __restrict__ feat,
                                                   float* __restrict__ out, int b) {
  int t = threadIdx.x, lane = t & 63, wv = t >> 6;
  int row = blockIdx.x * 4 + wv;                   // 784*4 = 3136
  float t0 = 1e30f, t1 = 1e30f, t2 = 1e30f;
  if (lane < 50) {
    const float* p = part + ((size_t)row * 50 + lane) * 3;
    ins3(p[0], t0, t1, t2); ins3(p[1], t0, t1, t2); ins3(p[2], t0, t1, t2);
  }
  #pragma unroll
  for (int m = 1; m < 64; m <<= 1) {
    float u0 = __shfl_xor(t0, m, 64);
    float u1 = __shfl_xor(t1, m, 64);
    float u2 = __shfl_xor(t2, m, 64);
    ins3(u0, t0, t1, t2); ins3(u1, t0, t1, t2); ins3(u2, t0, t1, t2);
  }
  if (lane == 0) {
    float ft = feat[row];
    float v0 = sqrtf(fmaxf(ft + t0, 0.f));
    float v1 = sqrtf(fmaxf(ft + t1, 0.f));
    float v2 = sqrtf(fmaxf(ft + t2, 0.f));
    float w0 = 1.f / (1.f + expf(v0 - v1) + expf(v0 - v2));
    out[b * HWo + row] = v0 * w0;
  }
}

// ---------------- launch ----------------
extern "C" void kernel_launch(void* const* d_in, const int* in_sizes, int n_in,
                              void* d_out, int out_size, void* d_ws, size_t ws_size,
                              hipStream_t stream) {
  const float* p1   = (const float*)d_in[0];
  const float* p2   = (const float*)d_in[1];
  const float* p3   = (const float*)d_in[2];
  const float* Wm   = (const float*)d_in[3];
  const float* bias = (const float*)d_in[4];
  const float* Cm   = (const float*)d_in[5];
  float* out = (float*)d_out;

  // workspace (~49.1 MB), 256B-aligned slices
  char* ws = (char*)d_ws;
  size_t off = 0;
  uint16_t* Wh     = (uint16_t*)(ws + off); off += (size_t)ODIM * KP1 * 2;          // 6,651,904
  uint16_t* Ct     = (uint16_t*)(ws + off); off += (size_t)NP * ODIM * 2;           // 11,468,800
  float*    cent   = (float*)(ws + off);    off += 16384;
  float*    feat   = (float*)(ws + off);    off += 16384;
  float*    part   = (float*)(ws + off);    off += (size_t)NP * 50 * 3 * 4;         // 1,920,000
  float*    pooled = (float*)(ws + off);    off += (size_t)(P1SZ + P2SZ + P3SZ) * 4;// 5,619,712
  uint16_t* xcb    = (uint16_t*)(ws + off); off += (size_t)NP * KP1 * 2;            // 11,878,400
  uint16_t* phi_t  = (uint16_t*)(ws + off); off += (size_t)NP * ODIM * 2;           // 11,468,800

  convW_kernel<<<(ODIM * KP1) / 256, 256, 0, stream>>>(Wm, Wh);
  convC_kernel<<<(NCENT * ODIM) / 256, 256, 0, stream>>>(Cm, Ct);
  cent_kernel<<<NP / 4, 256, 0, stream>>>(Ct, cent);

  for (int b = 0; b < NB; ++b) {
    pool_kernel<<<(P1SZ + P2SZ + P3SZ) / 256, 256, 0, stream>>>(p1, p2, p3, pooled, b);
    assemble_kernel<<<(HWo * KP1) / 256, 256, 0, stream>>>(pooled, xcb, feat);
    gemm1_mfma<<<dim3(NP / 128, ODIM / 128), 256, 0, stream>>>(Wh, bias, xcb, phi_t, feat);
    gemm2_mfma<<<dim3(NP / 128, NP / 128), 256, 0, stream>>>(phi_t, Ct, cent, part);
    merge_score<<<784, 256, 0, stream>>>(part, feat, out, b);
  }
}

// Round 6
// 2514.911 us; speedup vs baseline: 1.1166x; 1.1166x over previous
//
#include <hip/hip_runtime.h>
#include <math.h>
#include <stdint.h>

typedef float f32x4 __attribute__((ext_vector_type(4)));
typedef short short8 __attribute__((ext_vector_type(8)));

#define GLOBAL_AS __attribute__((address_space(1)))
#define LDS_AS __attribute__((address_space(3)))

static constexpr int HWo   = 3136;   // 56*56
static constexpr int NB    = 8;
static constexpr int NP    = 3200;   // padded pixel/centroid count (25*128)
static constexpr int KDIM  = 1794;   // 1792 + 2 coord channels
static constexpr int KP1   = 1856;   // gemm1 K padded to 29*64
static constexpr int ODIM  = 1792;   // gemm2 K = 28*64
static constexpr int NCENT = 3136;

__device__ __forceinline__ uint16_t f2bf(float f) {
  union { float f; uint32_t u; } v; v.f = f;
  uint32_t u = v.u;
  return (uint16_t)((u + 0x7FFFu + ((u >> 16) & 1u)) >> 16);   // RNE
}
__device__ __forceinline__ float bf2f(uint16_t h) {
  union { uint32_t u; float f; } v; v.u = ((uint32_t)h) << 16;
  return v.f;
}

// ---------------- one-time converts ----------------
__global__ __launch_bounds__(256) void convW_kernel(const float* __restrict__ W, uint16_t* __restrict__ Wh) {
  int idx = blockIdx.x * 256 + threadIdx.x;          // 1792*1856 exact
  int o = idx / KP1, k = idx % KP1;
  float v = (k < KDIM) ? W[(size_t)o * KDIM + k] : 0.f;
  Wh[idx] = f2bf(v);
}

__global__ __launch_bounds__(256) void convC_kernel(const float* __restrict__ C, uint16_t* __restrict__ Ct) {
  int idx = blockIdx.x * 256 + threadIdx.x;          // 3136*1792 exact
  int j = idx / ODIM, o = idx % ODIM;
  Ct[(size_t)j * ODIM + o] = f2bf(C[(size_t)o * NCENT + j]);
}

// cent[j] = |C_col_j|^2 for j<3136, 1e30 sentinel for padded rows
__global__ __launch_bounds__(256) void cent_kernel(const uint16_t* __restrict__ Ct, float* __restrict__ cent) {
  int t = threadIdx.x, lane = t & 63, wv = t >> 6;
  int row = blockIdx.x * 4 + wv;                     // 800 blocks -> 3200 rows
  if (row >= NCENT) { if (lane == 0) cent[row] = 1e30f; return; }
  const uint32_t* p = (const uint32_t*)(Ct + (size_t)row * ODIM);
  float s = 0.f;
  #pragma unroll
  for (int it = 0; it < 14; ++it) {
    uint32_t u = p[it * 64 + lane];
    float a = bf2f((uint16_t)(u & 0xFFFF)), b = bf2f((uint16_t)(u >> 16));
    s += a * a + b * b;
  }
  #pragma unroll
  for (int m = 1; m < 64; m <<= 1) s += __shfl_xor(s, m, 64);
  if (lane == 0) cent[row] = s;
}

// ---------------- pooling (all 3 levels, native res, fp32) ----------------
static constexpr int P1SZ = 256 * 3136;
static constexpr int P2SZ = 512 * 784;
static constexpr int P3SZ = 1024 * 196;

__device__ __forceinline__ float pool9f(const float* __restrict__ p, int S, int y, int x) {
  float s = 0.f;
  for (int dy = -1; dy <= 1; ++dy) {
    int yy = y + dy; if (yy < 0 || yy >= S) continue;
    for (int dx = -1; dx <= 1; ++dx) {
      int xx = x + dx; if (xx < 0 || xx >= S) continue;
      s += p[yy * S + xx];
    }
  }
  return s * (1.f / 9.f);
}

__global__ __launch_bounds__(256) void pool_kernel(const float* __restrict__ p1, const float* __restrict__ p2,
                                                   const float* __restrict__ p3, float* __restrict__ pooled, int b) {
  int idx = blockIdx.x * 256 + threadIdx.x;          // 1404928 exact
  const float* src; int S, loc;
  if (idx < P1SZ)              { src = p1 + (size_t)b * P1SZ; S = 56; loc = idx; }
  else if (idx < P1SZ + P2SZ)  { src = p2 + (size_t)b * P2SZ; S = 28; loc = idx - P1SZ; }
  else                         { src = p3 + (size_t)b * P3SZ; S = 14; loc = idx - P1SZ - P2SZ; }
  int c = loc / (S * S), hw = loc % (S * S);
  pooled[idx] = pool9f(src + (size_t)c * S * S, S, hw / S, hw % S);
}

// ---------------- assemble xcb bf16 [3200][1856] pixel-major; also zero feat ----------------
__global__ __launch_bounds__(256) void assemble_kernel(const float* __restrict__ pooled, uint16_t* __restrict__ xcb,
                                                       float* __restrict__ feat) {
  int idx = blockIdx.x * 256 + threadIdx.x;          // 3136*1856 exact
  if (idx < NP) feat[idx] = 0.f;                     // zero feat for gemm1 atomics
  int i = idx / KP1, ch = idx % KP1;
  int x = i % 56, y = i / 56;
  float v;
  if (ch < 256) {
    v = pooled[ch * 3136 + i];
  } else if (ch < 1792) {
    const float* base; int S; float scale, shift;
    if (ch < 768) { base = pooled + P1SZ + (ch - 256) * 784;          S = 28; scale = 0.5f;  shift = -0.25f;  }
    else          { base = pooled + P1SZ + P2SZ + (ch - 768) * 196;   S = 14; scale = 0.25f; shift = -0.375f; }
    float sx = x * scale + shift, sy = y * scale + shift;
    float fx0 = floorf(sx), fy0 = floorf(sy);
    float fx = sx - fx0, fy = sy - fy0;
    int x0 = (int)fx0, y0 = (int)fy0, x1 = x0 + 1, y1 = y0 + 1;
    x0 = x0 < 0 ? 0 : x0; x1 = x1 > S - 1 ? S - 1 : x1;
    y0 = y0 < 0 ? 0 : y0; y1 = y1 > S - 1 ? S - 1 : y1;
    float v00 = base[y0 * S + x0], v01 = base[y0 * S + x1];
    float v10 = base[y1 * S + x0], v11 = base[y1 * S + x1];
    v = (1.f - fy) * ((1.f - fx) * v00 + fx * v01) + fy * ((1.f - fx) * v10 + fx * v11);
  } else if (ch == 1792) v = -1.f + 2.f * x / 55.f;
  else if (ch == 1793)   v = -1.f + 2.f * y / 55.f;
  else                   v = 0.f;                    // K padding: MUST be zero
  xcb[idx] = f2bf(v);
}

// ---------------- shared GEMM building blocks ----------------
// Stage a 128x64(bf16) tile via global_load_lds(16B) with XOR-8 chunk swizzle:
// LDS slot (r, c) holds global chunk c^(r&7) of row r. Linear LDS = lane-order (no pad).
__device__ __forceinline__ void stage_tile(uint16_t* lds, const uint16_t* __restrict__ g, int ldk, int t) {
  int wv = t >> 6;
  #pragma unroll
  for (int it = 0; it < 4; ++it) {
    int idx = it * 256 + t;                          // [0,1024): r=idx>>3, c=idx&7
    int r = idx >> 3, c = idx & 7;
    int cg = c ^ (r & 7);
    const uint16_t* src = g + (size_t)r * ldk + cg * 8;
    uint16_t* dst = lds + (size_t)(it * 256 + wv * 64) * 8;   // wave-uniform base; HW adds lane*16
    __builtin_amdgcn_global_load_lds((const GLOBAL_AS void*)src, (LDS_AS void*)dst, 16, 0, 0);
  }
}

// Read 8-short fragment of logical chunk (kk*4+quad) of row r (undo swizzle)
__device__ __forceinline__ short8 frag_ld(const uint16_t* lds, int r, int kk, int quad) {
  int sc = (kk * 4 + quad) ^ (r & 7);
  return *(const short8*)(lds + r * 64 + sc * 8);
}

__device__ __forceinline__ void ins3(float v, float& a, float& b, float& c) {
  if (v < c) {
    if (v < b) { c = b; if (v < a) { b = a; a = v; } else { b = v; } }
    else { c = v; }
  }
}

// ---------------- GEMM1: phi_t[i][o] = W[o][:]·xc[i][:] + bias[o]; feat[i] += |phi_i|^2 ----------------
__global__ __launch_bounds__(256) void gemm1_mfma(const uint16_t* __restrict__ Wh, const float* __restrict__ bias,
                                                  const uint16_t* __restrict__ xcb, uint16_t* __restrict__ phi_t,
                                                  float* __restrict__ feat) {
  __shared__ uint16_t As[128 * 64];
  __shared__ uint16_t Bs[128 * 64];
  int t = threadIdx.x;
  int row0 = blockIdx.y * 128;     // o
  int col0 = blockIdx.x * 128;     // pixel
  int lane = t & 63, wv = t >> 6, wm = wv & 1, wn = wv >> 1;
  int l15 = lane & 15, quad = lane >> 4;
  f32x4 acc[4][4] = {};
  for (int k0 = 0; k0 < KP1; k0 += 64) {
    stage_tile(As, Wh + (size_t)row0 * KP1 + k0, KP1, t);
    stage_tile(Bs, xcb + (size_t)col0 * KP1 + k0, KP1, t);
    __syncthreads();
    #pragma unroll
    for (int kk = 0; kk < 2; ++kk) {
      short8 a[4], b[4];
      #pragma unroll
      for (int i = 0; i < 4; ++i) a[i] = frag_ld(As, wm * 64 + i * 16 + l15, kk, quad);
      #pragma unroll
      for (int j = 0; j < 4; ++j) b[j] = frag_ld(Bs, wn * 64 + j * 16 + l15, kk, quad);
      #pragma unroll
      for (int i = 0; i < 4; ++i)
        #pragma unroll
        for (int j = 0; j < 4; ++j)
          acc[i][j] = __builtin_amdgcn_mfma_f32_16x16x32_bf16(a[i], b[j], acc[i][j], 0, 0, 0);
    }
    __syncthreads();
  }
  // D: col(l15)=pixel, row(quad*4+reg)=o
  float sq[4] = {0.f, 0.f, 0.f, 0.f};
  #pragma unroll
  for (int i = 0; i < 4; ++i) {
    int ob = row0 + wm * 64 + i * 16 + quad * 4;
    float4 bv = *(const float4*)&bias[ob];
    #pragma unroll
    for (int j = 0; j < 4; ++j) {
      int pix = col0 + wn * 64 + j * 16 + l15;
      float v0 = acc[i][j][0] + bv.x, v1 = acc[i][j][1] + bv.y;
      float v2 = acc[i][j][2] + bv.z, v3 = acc[i][j][3] + bv.w;
      ushort4 u; u.x = f2bf(v0); u.y = f2bf(v1); u.z = f2bf(v2); u.w = f2bf(v3);
      *(ushort4*)&phi_t[(size_t)pix * ODIM + ob] = u;
      sq[j] += v0 * v0 + v1 * v1 + v2 * v2 + v3 * v3;
    }
  }
  #pragma unroll
  for (int j = 0; j < 4; ++j) {
    sq[j] += __shfl_xor(sq[j], 16, 64);
    sq[j] += __shfl_xor(sq[j], 32, 64);
  }
  if (quad == 0) {
    #pragma unroll
    for (int j = 0; j < 4; ++j)
      atomicAdd(&feat[col0 + wn * 64 + j * 16 + l15], sq[j]);
  }
}

// ---------------- GEMM2 + fused top-3 (pixel-sequential, spill-free epilogue) ----------------
__global__ __launch_bounds__(256) void gemm2_mfma(const uint16_t* __restrict__ phi_t, const uint16_t* __restrict__ Ct,
                                                  const float* __restrict__ cent, float* __restrict__ part) {
  __shared__ uint16_t As[128 * 64];
  __shared__ uint16_t Bs[128 * 64];
  int t = threadIdx.x;
  int row0 = blockIdx.y * 128;     // pixel
  int col0 = blockIdx.x * 128;     // centroid
  int lane = t & 63, wv = t >> 6, wm = wv & 1, wn = wv >> 1;
  int l15 = lane & 15, quad = lane >> 4;
  f32x4 acc[4][4] = {};
  for (int k0 = 0; k0 < ODIM; k0 += 64) {
    stage_tile(As, phi_t + (size_t)row0 * ODIM + k0, ODIM, t);
    stage_tile(Bs, Ct + (size_t)col0 * ODIM + k0, ODIM, t);
    __syncthreads();
    #pragma unroll
    for (int kk = 0; kk < 2; ++kk) {
      short8 a[4], b[4];
      #pragma unroll
      for (int i = 0; i < 4; ++i) a[i] = frag_ld(As, wm * 64 + i * 16 + l15, kk, quad);
      #pragma unroll
      for (int j = 0; j < 4; ++j) b[j] = frag_ld(Bs, wn * 64 + j * 16 + l15, kk, quad);
      #pragma unroll
      for (int i = 0; i < 4; ++i)
        #pragma unroll
        for (int j = 0; j < 4; ++j)
          acc[i][j] = __builtin_amdgcn_mfma_f32_16x16x32_bf16(a[i], b[j], acc[i][j], 0, 0, 0);
    }
    __syncthreads();
  }
  // D: col(l15)=centroid q, row(quad*4+reg)=pixel p.
  // Pixel-sequential top-3: one triple live at a time (no T[16] arrays -> no spill).
  float cv0 = cent[col0 + wn * 64 +  0 + l15];
  float cv1 = cent[col0 + wn * 64 + 16 + l15];
  float cv2 = cent[col0 + wn * 64 + 32 + l15];
  float cv3 = cent[col0 + wn * 64 + 48 + l15];
  int cb = blockIdx.x * 2 + wn;                  // [0,50)
  #pragma unroll
  for (int i = 0; i < 4; ++i) {
    #pragma unroll
    for (int r = 0; r < 4; ++r) {
      float t0 = 1e30f, t1 = 1e30f, t2 = 1e30f;
      ins3(cv0 - 2.f * acc[i][0][r], t0, t1, t2);
      ins3(cv1 - 2.f * acc[i][1][r], t0, t1, t2);
      ins3(cv2 - 2.f * acc[i][2][r], t0, t1, t2);
      ins3(cv3 - 2.f * acc[i][3][r], t0, t1, t2);
      #pragma unroll
      for (int m = 1; m <= 8; m <<= 1) {
        float u0 = __shfl_xor(t0, m, 64);
        float u1 = __shfl_xor(t1, m, 64);
        float u2 = __shfl_xor(t2, m, 64);
        ins3(u0, t0, t1, t2); ins3(u1, t0, t1, t2); ins3(u2, t0, t1, t2);
      }
      if (l15 == 0) {
        int p = row0 + wm * 64 + i * 16 + quad * 4 + r;
        float* pp = part + ((size_t)p * 50 + cb) * 3;
        pp[0] = t0; pp[1] = t1; pp[2] = t2;
      }
    }
  }
}

// ---------------- merge 50 partial top-3 + softmin score, one wave per row ----------------
__global__ __launch_bounds__(256) void merge_score(const float* __restrict__ part, const float* __restrict__ feat,
                                                   float* __restrict__ out, int b) {
  int t = threadIdx.x, lane = t & 63, wv = t >> 6;
  int row = blockIdx.x * 4 + wv;                   // 784*4 = 3136
  float t0 = 1e30f, t1 = 1e30f, t2 = 1e30f;
  if (lane < 50) {
    const float* p = part + ((size_t)row * 50 + lane) * 3;
    ins3(p[0], t0, t1, t2); ins3(p[1], t0, t1, t2); ins3(p[2], t0, t1, t2);
  }
  #pragma unroll
  for (int m = 1; m < 64; m <<= 1) {
    float u0 = __shfl_xor(t0, m, 64);
    float u1 = __shfl_xor(t1, m, 64);
    float u2 = __shfl_xor(t2, m, 64);
    ins3(u0, t0, t1, t2); ins3(u1, t0, t1, t2); ins3(u2, t0, t1, t2);
  }
  if (lane == 0) {
    float ft = feat[row];
    float v0 = sqrtf(fmaxf(ft + t0, 0.f));
    float v1 = sqrtf(fmaxf(ft + t1, 0.f));
    float v2 = sqrtf(fmaxf(ft + t2, 0.f));
    float w0 = 1.f / (1.f + expf(v0 - v1) + expf(v0 - v2));
    out[b * HWo + row] = v0 * w0;
  }
}

// ---------------- launch ----------------
extern "C" void kernel_launch(void* const* d_in, const int* in_sizes, int n_in,
                              void* d_out, int out_size, void* d_ws, size_t ws_size,
                              hipStream_t stream) {
  const float* p1   = (const float*)d_in[0];
  const float* p2   = (const float*)d_in[1];
  const float* p3   = (const float*)d_in[2];
  const float* Wm   = (const float*)d_in[3];
  const float* bias = (const float*)d_in[4];
  const float* Cm   = (const float*)d_in[5];
  float* out = (float*)d_out;

  // workspace (~49.1 MB), 256B-aligned slices
  char* ws = (char*)d_ws;
  size_t off = 0;
  uint16_t* Wh     = (uint16_t*)(ws + off); off += (size_t)ODIM * KP1 * 2;          // 6,651,904
  uint16_t* Ct     = (uint16_t*)(ws + off); off += (size_t)NP * ODIM * 2;           // 11,468,800
  float*    cent   = (float*)(ws + off);    off += 16384;
  float*    feat   = (float*)(ws + off);    off += 16384;
  float*    part   = (float*)(ws + off);    off += (size_t)NP * 50 * 3 * 4;         // 1,920,000
  float*    pooled = (float*)(ws + off);    off += (size_t)(P1SZ + P2SZ + P3SZ) * 4;// 5,619,712
  uint16_t* xcb    = (uint16_t*)(ws + off); off += (size_t)NP * KP1 * 2;            // 11,878,400
  uint16_t* phi_t  = (uint16_t*)(ws + off); off += (size_t)NP * ODIM * 2;           // 11,468,800

  convW_kernel<<<(ODIM * KP1) / 256, 256, 0, stream>>>(Wm, Wh);
  convC_kernel<<<(NCENT * ODIM) / 256, 256, 0, stream>>>(Cm, Ct);
  cent_kernel<<<NP / 4, 256, 0, stream>>>(Ct, cent);

  for (int b = 0; b < NB; ++b) {
    pool_kernel<<<(P1SZ + P2SZ + P3SZ) / 256, 256, 0, stream>>>(p1, p2, p3, pooled, b);
    assemble_kernel<<<(HWo * KP1) / 256, 256, 0, stream>>>(pooled, xcb, feat);
    gemm1_mfma<<<dim3(NP / 128, ODIM / 128), 256, 0, stream>>>(Wh, bias, xcb, phi_t, feat);
    gemm2_mfma<<<dim3(NP / 128, NP / 128), 256, 0, stream>>>(phi_t, Ct, cent, part);
    merge_score<<<784, 256, 0, stream>>>(part, feat, out, b);
  }
}